// Round 1
// baseline (294.225 us; speedup 1.0000x reference)
//
#include <hip/hip_runtime.h>
#include <hip/hip_bf16.h>
#include <math.h>

typedef __hip_bfloat16 bf16;
typedef __attribute__((ext_vector_type(8))) short s16x8;   // 8 bf16 (4 VGPRs)
typedef __attribute__((ext_vector_type(4))) float f32x4;

// dims
#define B_IN 512
#define B_HID 1024
#define B_MEM 1024
#define B_OUT 512
#define NBATCH 4096

__device__ __forceinline__ float sigmoidf_(float x) { return 1.0f / (1.0f + expf(-x)); }

// ---------------- small fp32 matvec helper: one wave computes dot(row, v) ----------------
__device__ __forceinline__ float wave_dot(const float* __restrict__ row,
                                          const float* __restrict__ v,
                                          int n, int lane) {
  float s = 0.0f;
  for (int i = lane * 4; i < n; i += 256) {
    const float4 a = *(const float4*)(row + i);
    const float4 b = *(const float4*)(v + i);
    s += a.x * b.x + a.y * b.y + a.z * b.z + a.w * b.w;
  }
#pragma unroll
  for (int off = 32; off > 0; off >>= 1) s += __shfl_down(s, off, 64);
  return s;  // valid in lane 0
}

// ---------------- recurrence phase 1: gate args (4 waves/block, 256 blocks, j = wave id) ----
// mode 0 (steps 0..3): write rgm = sig(arg_rg)*mem, h0 = sig(arg_bi)*sig(arg_ig), wg = sig(arg_wg)
// mode 1 (final):      write raw constants c_bi, c_ig, c_rg for the batched step 4
__global__ void step_gates(
    const float* __restrict__ Wri, const float* __restrict__ b_inp, const float* __restrict__ b_rinp,
    const float* __restrict__ Wmig, const float* __restrict__ Wrig,
    const float* __restrict__ b_ig, const float* __restrict__ b_mig, const float* __restrict__ b_rig,
    const float* __restrict__ Wmrg, const float* __restrict__ Wrrg,
    const float* __restrict__ b_rg, const float* __restrict__ b_mrg, const float* __restrict__ b_rrg,
    const float* __restrict__ Wmwg, const float* __restrict__ Wrwg,
    const float* __restrict__ b_wg, const float* __restrict__ b_mwg, const float* __restrict__ b_rwg,
    const float* __restrict__ out_s, const float* __restrict__ mem_s,
    float* __restrict__ rgm, float* __restrict__ h0v, float* __restrict__ wgv,
    float* __restrict__ c_bi, float* __restrict__ c_ig, float* __restrict__ c_rg,
    int mode) {
  const int lane = threadIdx.x & 63;
  const int j = blockIdx.x * 4 + (threadIdx.x >> 6);  // 0..1023
  const float dbi = wave_dot(Wri + (size_t)j * 512, out_s, 512, lane);
  const float dig = wave_dot(Wmig + (size_t)j * 1024, mem_s, 1024, lane) +
                    wave_dot(Wrig + (size_t)j * 512, out_s, 512, lane);
  const float drg = wave_dot(Wmrg + (size_t)j * 1024, mem_s, 1024, lane) +
                    wave_dot(Wrrg + (size_t)j * 512, out_s, 512, lane);
  if (mode == 0) {
    const float dwg = wave_dot(Wmwg + (size_t)j * 1024, mem_s, 1024, lane) +
                      wave_dot(Wrwg + (size_t)j * 512, out_s, 512, lane);
    if (lane == 0) {
      const float abi = b_inp[j] + b_rinp[j] + dbi;
      const float aig = b_ig[j] + b_mig[j] + b_rig[j] + dig;
      const float arg = b_rg[j] + b_mrg[j] + b_rrg[j] + drg;
      const float awg = b_wg[j] + b_mwg[j] + b_rwg[j] + dwg;
      rgm[j] = sigmoidf_(arg) * mem_s[j];
      h0v[j] = sigmoidf_(abi) * sigmoidf_(aig);
      wgv[j] = sigmoidf_(awg);
    }
  } else {
    if (lane == 0) {
      c_bi[j] = b_inp[j] + b_rinp[j] + dbi;
      c_ig[j] = b_ig[j] + b_mig[j] + b_rig[j] + dig;
      c_rg[j] = b_rg[j] + b_mrg[j] + b_rrg[j] + drg;
    }
  }
}

// ---------------- recurrence phase 2: hidden = b_dec + W_dec . rgm + h0 ----------------
__global__ void step_decode(const float* __restrict__ Wdec, const float* __restrict__ b_dec,
                            const float* __restrict__ rgm, const float* __restrict__ h0v,
                            float* __restrict__ hidv) {
  const int lane = threadIdx.x & 63;
  const int j = blockIdx.x * 4 + (threadIdx.x >> 6);
  const float d = wave_dot(Wdec + (size_t)j * 1024, rgm, 1024, lane);
  if (lane == 0) hidv[j] = b_dec[j] + d + h0v[j];
}

// ---------------- recurrence phase 3: mem update + out matvec ----------------
__global__ void step_update(const float* __restrict__ Wenc, const float* __restrict__ b_enc,
                            const float* __restrict__ Who, const float* __restrict__ hidv,
                            const float* __restrict__ wgv, float* __restrict__ mem_s,
                            float* __restrict__ out_s) {
  const int lane = threadIdx.x & 63;
  const int w = blockIdx.x * 4 + (threadIdx.x >> 6);  // 0..1535
  if (w < 1024) {
    const float d = wave_dot(Wenc + (size_t)w * 1024, hidv, 1024, lane);
    if (lane == 0) {
      const float enc = tanhf(b_enc[w] + d);
      const float wg = wgv[w];
      mem_s[w] = (1.0f - wg) * mem_s[w] + wg * enc;
    }
  } else {
    const int o = w - 1024;
    const float d = wave_dot(Who + (size_t)o * 1024, hidv, 1024, lane);
    if (lane == 0) out_s[o] = d;
  }
}

// ---------------- conversions: fp32 weights -> bf16, + zero-init state ----------------
__global__ void prep(const float* __restrict__ W_inp, const float* __restrict__ W_ig,
                     const float* __restrict__ W_rg, const float* __restrict__ W_ho,
                     bf16* __restrict__ Wi, bf16* __restrict__ Wg, bf16* __restrict__ Wr,
                     bf16* __restrict__ Wo, float* __restrict__ out_s, float* __restrict__ mem_s) {
  const int NW = 1024 * 512;
  int i = blockIdx.x * 256 + threadIdx.x;
  if (i < NW) {
    Wi[i] = __float2bfloat16(W_inp[i]);
  } else if (i < 2 * NW) {
    Wg[i - NW] = __float2bfloat16(W_ig[i - NW]);
  } else if (i < 3 * NW) {
    Wr[i - 2 * NW] = __float2bfloat16(W_rg[i - 2 * NW]);
  } else if (i < 4 * NW) {
    Wo[i - 3 * NW] = __float2bfloat16(W_ho[i - 3 * NW]);
  } else if (i < 4 * NW + 1536) {
    const int t = i - 4 * NW;
    if (t < 512) out_s[t] = 0.0f;
    else mem_s[t - 512] = 0.0f;
  }
}

// ---------------- transpose input [512][4096] fp32 -> Xb [4096][512] bf16 ----------------
__global__ void transpose_cast(const float* __restrict__ in, bf16* __restrict__ Xb) {
  __shared__ float tile[32][33];
  const int i0 = blockIdx.y * 32;  // input-dim
  const int b0 = blockIdx.x * 32;  // batch-dim
  const int tx = threadIdx.x & 31, ty = threadIdx.x >> 5;  // 32 x 8
#pragma unroll
  for (int r = ty; r < 32; r += 8) tile[r][tx] = in[(size_t)(i0 + r) * 4096 + b0 + tx];
  __syncthreads();
#pragma unroll
  for (int r = ty; r < 32; r += 8)
    Xb[(size_t)(b0 + r) * 512 + i0 + tx] = __float2bfloat16(tile[tx][r]);
}

// ---------------- Wd_scaled[j][k] = W_decoder[j][k] * mem3[k]  (bf16) ----------------
__global__ void scale_dec(const float* __restrict__ Wdec, const float* __restrict__ mem_s,
                          bf16* __restrict__ Wd) {
  const int i = blockIdx.x * 256 + threadIdx.x;  // 1M
  Wd[i] = __float2bfloat16(Wdec[i] * mem_s[i & 1023]);
}

// ---------------- MFMA GEMM: C[M,N] = A[M,K] . B[N,K]^T, 128x128 tile, BK=64 ----------------
// NG = number of B matrices sharing A (3 for the fused gate GEMM).
// EPI 0: gates (G bf16, H0 fp32); EPI 1: hidden = acc + b_dec + H0 -> bf16; EPI 2: fp32 out.
template <int NG, int EPI>
__global__ __launch_bounds__(256) void gemm_bt(
    const bf16* __restrict__ A, const bf16* __restrict__ B0, const bf16* __restrict__ B1,
    const bf16* __restrict__ B2, const int K, const float* __restrict__ v0,
    const float* __restrict__ v1, const float* __restrict__ v2, const float* __restrict__ Hadd,
    bf16* __restrict__ outB, float* __restrict__ outF) {
  __shared__ bf16 smem[(1 + NG) * 8192];  // A tile + NG B tiles, each 128x64 bf16 (16KB)
  const int tid = threadIdx.x;
  const int wave = tid >> 6, lane = tid & 63;
  const int wm = wave >> 1, wn = wave & 1;
  const int m0 = blockIdx.y * 128, n0 = blockIdx.x * 128;

  f32x4 acc[NG][4][4] = {};

  for (int kt = 0; kt < K; kt += 64) {
    __syncthreads();
    // stage A tile: 1024 16B-chunks; LDS chunk (row, s) holds global chunk s ^ (row&7)
#pragma unroll
    for (int i = 0; i < 4; ++i) {
      const int ci = i * 256 + tid;
      const int row = ci >> 3, sck = ci & 7;
      const int ck = sck ^ (row & 7);
      const bf16* g = A + (size_t)(m0 + row) * K + kt + ck * 8;
      const unsigned lofs = (unsigned)__builtin_amdgcn_readfirstlane((i * 256 + wave * 64) * 16);
      __builtin_amdgcn_global_load_lds(
          (const __attribute__((address_space(1))) void*)g,
          (__attribute__((address_space(3))) void*)((char*)smem + lofs), 16, 0, 0);
    }
#pragma unroll
    for (int gI = 0; gI < NG; ++gI) {
      const bf16* Bp = (gI == 0) ? B0 : ((gI == 1) ? B1 : B2);
#pragma unroll
      for (int i = 0; i < 4; ++i) {
        const int ci = i * 256 + tid;
        const int row = ci >> 3, sck = ci & 7;
        const int ck = sck ^ (row & 7);
        const bf16* g = Bp + (size_t)(n0 + row) * K + kt + ck * 8;
        const unsigned lofs = (unsigned)__builtin_amdgcn_readfirstlane(
            (1 + gI) * 16384 + (i * 256 + wave * 64) * 16);
        __builtin_amdgcn_global_load_lds(
            (const __attribute__((address_space(1))) void*)g,
            (__attribute__((address_space(3))) void*)((char*)smem + lofs), 16, 0, 0);
      }
    }
    __syncthreads();  // drains vmcnt for the global_load_lds queue

#pragma unroll
    for (int ks = 0; ks < 2; ++ks) {
      const int ckk = ks * 4 + (lane >> 4);  // k-chunk index 0..7
      s16x8 af[4];
#pragma unroll
      for (int i = 0; i < 4; ++i) {
        const int R = wm * 64 + i * 16 + (lane & 15);
        af[i] = *(const s16x8*)((const char*)smem + (R * 8 + (ckk ^ (R & 7))) * 16);
      }
#pragma unroll
      for (int gI = 0; gI < NG; ++gI) {
        const char* sB = (const char*)smem + (1 + gI) * 16384;
#pragma unroll
        for (int j = 0; j < 4; ++j) {
          const int R = wn * 64 + j * 16 + (lane & 15);
          const s16x8 bfr = *(const s16x8*)(sB + (R * 8 + (ckk ^ (R & 7))) * 16);
#pragma unroll
          for (int i = 0; i < 4; ++i)
            acc[gI][i][j] =
                __builtin_amdgcn_mfma_f32_16x16x32_bf16(af[i], bfr, acc[gI][i][j], 0, 0, 0);
        }
      }
    }
  }

  // epilogue: C/D layout col = lane&15 (N side), row = (lane>>4)*4 + reg (M side)
  const int mb = (lane >> 4) * 4;
  const int nb = lane & 15;
#pragma unroll
  for (int i = 0; i < 4; ++i) {
#pragma unroll
    for (int j = 0; j < 4; ++j) {
      const int col = n0 + wn * 64 + j * 16 + nb;
#pragma unroll
      for (int r = 0; r < 4; ++r) {
        const int rowg = m0 + wm * 64 + i * 16 + mb + r;
        if (EPI == 0) {
          const float bi = sigmoidf_(acc[0][i][j][r] + v0[col]);
          const float ig = sigmoidf_(acc[1][i][j][r] + v1[col]);
          const float rg = sigmoidf_(acc[NG - 1][i][j][r] + v2[col]);
          outB[(size_t)rowg * 1024 + col] = __float2bfloat16(rg);
          outF[(size_t)rowg * 1024 + col] = bi * ig;
        } else if (EPI == 1) {
          const float h = acc[0][i][j][r] + v0[col] + Hadd[(size_t)rowg * 1024 + col];
          outB[(size_t)rowg * 1024 + col] = __float2bfloat16(h);
        } else {
          outF[(size_t)rowg * 512 + col] = acc[0][i][j][r];
        }
      }
    }
  }
}

extern "C" void kernel_launch(void* const* d_in, const int* in_sizes, int n_in, void* d_out,
                              int out_size, void* d_ws, size_t ws_size, hipStream_t stream) {
  const float* input  = (const float*)d_in[0];
  const float* W_ig   = (const float*)d_in[1];  const float* b_ig   = (const float*)d_in[2];
  const float* W_rig  = (const float*)d_in[3];  const float* b_rig  = (const float*)d_in[4];
  const float* W_mig  = (const float*)d_in[5];  const float* b_mig  = (const float*)d_in[6];
  const float* W_inp  = (const float*)d_in[7];  const float* b_inp  = (const float*)d_in[8];
  const float* W_rinp = (const float*)d_in[9];  const float* b_rinp = (const float*)d_in[10];
  const float* W_rg   = (const float*)d_in[11]; const float* b_rg   = (const float*)d_in[12];
  const float* W_rrg  = (const float*)d_in[13]; const float* b_rrg  = (const float*)d_in[14];
  const float* W_mrg  = (const float*)d_in[15]; const float* b_mrg  = (const float*)d_in[16];
  const float* W_dec  = (const float*)d_in[17]; const float* b_dec  = (const float*)d_in[18];
  const float* W_wg   = (const float*)d_in[19]; const float* b_wg   = (const float*)d_in[20];
  const float* W_rwg  = (const float*)d_in[21]; const float* b_rwg  = (const float*)d_in[22];
  const float* W_mwg  = (const float*)d_in[23]; const float* b_mwg  = (const float*)d_in[24];
  const float* W_enc  = (const float*)d_in[25]; const float* b_enc  = (const float*)d_in[26];
  const float* W_ho   = (const float*)d_in[27];

  char* ws = (char*)d_ws;
  float* out_s = (float*)(ws + 0);        // 512
  float* mem_s = (float*)(ws + 2048);     // 1024
  float* rgm   = (float*)(ws + 6144);     // 1024
  float* h0v   = (float*)(ws + 10240);    // 1024
  float* wgv   = (float*)(ws + 14336);    // 1024
  float* hidv  = (float*)(ws + 18432);    // 1024
  float* c_bi  = (float*)(ws + 22528);    // 1024
  float* c_ig  = (float*)(ws + 26624);    // 1024
  float* c_rg  = (float*)(ws + 30720);    // 1024
  bf16* Xb  = (bf16*)(ws + 65536);                 // [4096][512]
  bf16* Wi  = (bf16*)(ws + 65536 + 4194304);       // [1024][512]
  bf16* Wg  = (bf16*)(ws + 65536 + 5242880);       // [1024][512]
  bf16* Wr  = (bf16*)(ws + 65536 + 6291456);       // [1024][512]
  bf16* Wo  = (bf16*)(ws + 65536 + 7340032);       // [512][1024]
  bf16* Wd  = (bf16*)(ws + 65536 + 8388608);       // [1024][1024]
  bf16* G   = (bf16*)(ws + 65536 + 10485760);      // [4096][1024]
  float* H0 = (float*)(ws + 65536 + 18874368);     // [4096][1024]
  bf16* Hid = (bf16*)(ws + 65536 + 35651584);      // [4096][1024]

  // static conversions + zero state
  prep<<<8198, 256, 0, stream>>>(W_inp, W_ig, W_rg, W_ho, Wi, Wg, Wr, Wo, out_s, mem_s);
  transpose_cast<<<dim3(128, 16), 256, 0, stream>>>(input, Xb);

  // steps 0..3: batch-invariant recurrence at B=1 (fp32)
  for (int s = 0; s < 4; ++s) {
    step_gates<<<256, 256, 0, stream>>>(W_rinp, b_inp, b_rinp, W_mig, W_rig, b_ig, b_mig, b_rig,
                                        W_mrg, W_rrg, b_rg, b_mrg, b_rrg, W_mwg, W_rwg, b_wg,
                                        b_mwg, b_rwg, out_s, mem_s, rgm, h0v, wgv, c_bi, c_ig,
                                        c_rg, 0);
    step_decode<<<256, 256, 0, stream>>>(W_dec, b_dec, rgm, h0v, hidv);
    step_update<<<384, 256, 0, stream>>>(W_enc, b_enc, W_ho, hidv, wgv, mem_s, out_s);
  }
  // step 4 constants + mem-folded decoder weights
  step_gates<<<256, 256, 0, stream>>>(W_rinp, b_inp, b_rinp, W_mig, W_rig, b_ig, b_mig, b_rig,
                                      W_mrg, W_rrg, b_rg, b_mrg, b_rrg, W_mwg, W_rwg, b_wg, b_mwg,
                                      b_rwg, out_s, mem_s, rgm, h0v, wgv, c_bi, c_ig, c_rg, 1);
  scale_dec<<<4096, 256, 0, stream>>>(W_dec, mem_s, Wd);

  // step 4 batched: gates -> hidden -> out
  gemm_bt<3, 0><<<dim3(8, 32), 256, 0, stream>>>(Xb, Wi, Wg, Wr, 512, c_bi, c_ig, c_rg, nullptr,
                                                 G, H0);
  gemm_bt<1, 1><<<dim3(8, 32), 256, 0, stream>>>(G, Wd, nullptr, nullptr, 1024, b_dec, nullptr,
                                                 nullptr, H0, Hid, nullptr);
  gemm_bt<1, 2><<<dim3(4, 32), 256, 0, stream>>>(Hid, Wo, nullptr, nullptr, 1024, nullptr,
                                                 nullptr, nullptr, nullptr, nullptr,
                                                 (float*)d_out);
}

// Round 2
// 245.466 us; speedup vs baseline: 1.1986x; 1.1986x over previous
//
#include <hip/hip_runtime.h>
#include <hip/hip_bf16.h>
#include <math.h>

typedef __hip_bfloat16 bf16;
typedef __attribute__((ext_vector_type(8))) short s16x8;   // 8 bf16 (4 VGPRs)
typedef __attribute__((ext_vector_type(4))) float f32x4;

__device__ __forceinline__ float sigf(float x) { return 1.0f / (1.0f + expf(-x)); }
__device__ __forceinline__ float dot4(float4 a, float4 b) {
  return a.x * b.x + a.y * b.y + a.z * b.z + a.w * b.w;
}

// ================= setup mega-kernel =================
// blocks [0,8198): cast Wcat ([Winp|Wig|Wrg] -> [3072][512] bf16), WhoB + Wcat2-left, zero state
// blocks [8198,10246): transpose input [512][4096] f32 -> Xb [4096][512] bf16   (128 x 16 tiles)
// blocks [10246,11270): Wdt[k][j] = bf16(W_dec[j][k])                           (32 x 32 tiles)
// blocks [11270,11274): step-0 closed form: hidv = b_dec + sig*sig, wgv = sig
__global__ void setup(const float* __restrict__ W_inp, const float* __restrict__ W_ig,
                      const float* __restrict__ W_rg, const float* __restrict__ W_ho,
                      const float* __restrict__ W_dec, const float* __restrict__ input,
                      const float* __restrict__ b_inp, const float* __restrict__ b_rinp,
                      const float* __restrict__ b_ig, const float* __restrict__ b_mig,
                      const float* __restrict__ b_rig, const float* __restrict__ b_wg,
                      const float* __restrict__ b_mwg, const float* __restrict__ b_rwg,
                      const float* __restrict__ b_dec, bf16* __restrict__ Wcat,
                      bf16* __restrict__ WhoB, bf16* __restrict__ Wcat2, bf16* __restrict__ Wdt,
                      bf16* __restrict__ Xb, float* __restrict__ out_s, float* __restrict__ mem_s,
                      float* __restrict__ hidv, float* __restrict__ wgv) {
  __shared__ float t[32][33];
  const int id = blockIdx.x, tid = threadIdx.x;
  if (id < 8198) {
    const int i = id * 256 + tid;
    if (i < 524288) {
      Wcat[i] = __float2bfloat16(W_inp[i]);
    } else if (i < 1048576) {
      Wcat[i] = __float2bfloat16(W_ig[i - 524288]);
    } else if (i < 1572864) {
      Wcat[i] = __float2bfloat16(W_rg[i - 1048576]);
    } else if (i < 2097152) {
      const int k = i - 1572864;
      const bf16 vv = __float2bfloat16(W_ho[k]);
      WhoB[k] = vv;
      Wcat2[(size_t)(k >> 10) * 2048 + (k & 1023)] = vv;
    } else if (i < 2098688) {
      const int tt = i - 2097152;
      if (tt < 512) out_s[tt] = 0.0f;
      else mem_s[tt - 512] = 0.0f;
    }
  } else if (id < 10246) {
    const int b = id - 8198;
    const int i0 = (b >> 7) * 32, b0 = (b & 127) * 32;
    const int tx = tid & 31, ty = tid >> 5;
#pragma unroll
    for (int r = ty; r < 32; r += 8) t[r][tx] = input[(size_t)(i0 + r) * 4096 + b0 + tx];
    __syncthreads();
#pragma unroll
    for (int r = ty; r < 32; r += 8)
      Xb[(size_t)(b0 + r) * 512 + i0 + tx] = __float2bfloat16(t[tx][r]);
  } else if (id < 11270) {
    const int b = id - 10246;
    const int j0 = (b >> 5) * 32, k0 = (b & 31) * 32;
    const int tx = tid & 31, ty = tid >> 5;
#pragma unroll
    for (int r = ty; r < 32; r += 8) t[r][tx] = W_dec[(size_t)(j0 + r) * 1024 + k0 + tx];
    __syncthreads();
#pragma unroll
    for (int r = ty; r < 32; r += 8)
      Wdt[(size_t)(k0 + r) * 1024 + j0 + tx] = __float2bfloat16(t[tx][r]);
  } else {
    const int j = (id - 11270) * 256 + tid;  // < 1024
    const float bi = sigf(b_inp[j] + b_rinp[j]);
    const float ig = sigf(b_ig[j] + b_mig[j] + b_rig[j]);
    hidv[j] = b_dec[j] + bi * ig;
    wgv[j] = sigf(b_wg[j] + b_mwg[j] + b_rwg[j]);
  }
}

// ================= recurrence: block-per-output-row kernels =================
__global__ void step_gates(const float* __restrict__ Wri, const float* __restrict__ Wmig,
                           const float* __restrict__ Wrig, const float* __restrict__ Wmrg,
                           const float* __restrict__ Wrrg, const float* __restrict__ Wmwg,
                           const float* __restrict__ Wrwg, const float* __restrict__ b_inp,
                           const float* __restrict__ b_rinp, const float* __restrict__ b_ig,
                           const float* __restrict__ b_mig, const float* __restrict__ b_rig,
                           const float* __restrict__ b_rg, const float* __restrict__ b_mrg,
                           const float* __restrict__ b_rrg, const float* __restrict__ b_wg,
                           const float* __restrict__ b_mwg, const float* __restrict__ b_rwg,
                           const float* __restrict__ out_s, const float* __restrict__ mem_s,
                           float* __restrict__ rgm, float* __restrict__ h0v,
                           float* __restrict__ wgv) {
  __shared__ float red[7][4];
  const int j = blockIdx.x, tid = threadIdx.x, lane = tid & 63, wave = tid >> 6;
  const float4 z = make_float4(0.f, 0.f, 0.f, 0.f);
  const float4 o4 = (tid < 128) ? *(const float4*)(out_s + tid * 4) : z;
  const float4 m4 = *(const float4*)(mem_s + tid * 4);
  float p[7];
  p[0] = dot4((tid < 128) ? *(const float4*)(Wri + (size_t)j * 512 + tid * 4) : z, o4);
  p[1] = dot4(*(const float4*)(Wmig + (size_t)j * 1024 + tid * 4), m4);
  p[2] = dot4((tid < 128) ? *(const float4*)(Wrig + (size_t)j * 512 + tid * 4) : z, o4);
  p[3] = dot4(*(const float4*)(Wmrg + (size_t)j * 1024 + tid * 4), m4);
  p[4] = dot4((tid < 128) ? *(const float4*)(Wrrg + (size_t)j * 512 + tid * 4) : z, o4);
  p[5] = dot4(*(const float4*)(Wmwg + (size_t)j * 1024 + tid * 4), m4);
  p[6] = dot4((tid < 128) ? *(const float4*)(Wrwg + (size_t)j * 512 + tid * 4) : z, o4);
#pragma unroll
  for (int d = 0; d < 7; ++d) {
    float s = p[d];
#pragma unroll
    for (int off = 32; off > 0; off >>= 1) s += __shfl_down(s, off, 64);
    if (lane == 0) red[d][wave] = s;
  }
  __syncthreads();
  if (tid == 0) {
    float D[7];
#pragma unroll
    for (int d = 0; d < 7; ++d) D[d] = red[d][0] + red[d][1] + red[d][2] + red[d][3];
    const float abi = b_inp[j] + b_rinp[j] + D[0];
    const float aig = b_ig[j] + b_mig[j] + b_rig[j] + D[1] + D[2];
    const float arg = b_rg[j] + b_mrg[j] + b_rrg[j] + D[3] + D[4];
    const float awg = b_wg[j] + b_mwg[j] + b_rwg[j] + D[5] + D[6];
    rgm[j] = sigf(arg) * mem_s[j];
    h0v[j] = sigf(abi) * sigf(aig);
    wgv[j] = sigf(awg);
  }
}

__global__ void step_decode(const float* __restrict__ Wdec, const float* __restrict__ b_dec,
                            const float* __restrict__ rgm, const float* __restrict__ h0v,
                            float* __restrict__ hidv) {
  __shared__ float red[4];
  const int j = blockIdx.x, tid = threadIdx.x;
  const float4 a = *(const float4*)(Wdec + (size_t)j * 1024 + tid * 4);
  const float4 b = *(const float4*)(rgm + tid * 4);
  float s = dot4(a, b);
#pragma unroll
  for (int off = 32; off > 0; off >>= 1) s += __shfl_down(s, off, 64);
  if ((tid & 63) == 0) red[tid >> 6] = s;
  __syncthreads();
  if (tid == 0) hidv[j] = b_dec[j] + red[0] + red[1] + red[2] + red[3] + h0v[j];
}

__global__ void step_update(const float* __restrict__ Wenc, const float* __restrict__ b_enc,
                            const float* __restrict__ Who, const float* __restrict__ hidv,
                            const float* __restrict__ wgv, float* __restrict__ mem_s,
                            float* __restrict__ out_s) {
  __shared__ float red[4];
  const int id = blockIdx.x, tid = threadIdx.x;
  const float* row = (id < 1024) ? (Wenc + (size_t)id * 1024) : (Who + (size_t)(id - 1024) * 1024);
  const float4 a = *(const float4*)(row + tid * 4);
  const float4 b = *(const float4*)(hidv + tid * 4);
  float s = dot4(a, b);
#pragma unroll
  for (int off = 32; off > 0; off >>= 1) s += __shfl_down(s, off, 64);
  if ((tid & 63) == 0) red[tid >> 6] = s;
  __syncthreads();
  if (tid == 0) {
    const float d = red[0] + red[1] + red[2] + red[3];
    if (id < 1024) {
      const float wg = wgv[id];
      mem_s[id] = (1.0f - wg) * mem_s[id] + wg * tanhf(b_enc[id] + d);
    } else {
      out_s[id - 1024] = d;
    }
  }
}

// ================= step-4 constants + vout + M1 scale =================
// blocks [0,1024): ccat = [c_bi|c_ig|c_rg];  [1024,1536): vout = Who . b_dec;
// blocks [1536,3584): Wcat2[:,1024:2048] = bf16(P * mem3)
__global__ void final_consts(const float* __restrict__ Wri, const float* __restrict__ Wmig,
                             const float* __restrict__ Wrig, const float* __restrict__ Wmrg,
                             const float* __restrict__ Wrrg, const float* __restrict__ b_inp,
                             const float* __restrict__ b_rinp, const float* __restrict__ b_ig,
                             const float* __restrict__ b_mig, const float* __restrict__ b_rig,
                             const float* __restrict__ b_rg, const float* __restrict__ b_mrg,
                             const float* __restrict__ b_rrg, const float* __restrict__ b_dec,
                             const float* __restrict__ Who, const float* __restrict__ out_s,
                             const float* __restrict__ mem_s, const float* __restrict__ P,
                             float* __restrict__ ccat, float* __restrict__ vout,
                             bf16* __restrict__ Wcat2) {
  __shared__ float red[5][4];
  const int id = blockIdx.x, tid = threadIdx.x, lane = tid & 63, wave = tid >> 6;
  if (id < 1024) {
    const float4 z = make_float4(0.f, 0.f, 0.f, 0.f);
    const float4 o4 = (tid < 128) ? *(const float4*)(out_s + tid * 4) : z;
    const float4 m4 = *(const float4*)(mem_s + tid * 4);
    float p[5];
    p[0] = dot4((tid < 128) ? *(const float4*)(Wri + (size_t)id * 512 + tid * 4) : z, o4);
    p[1] = dot4(*(const float4*)(Wmig + (size_t)id * 1024 + tid * 4), m4);
    p[2] = dot4((tid < 128) ? *(const float4*)(Wrig + (size_t)id * 512 + tid * 4) : z, o4);
    p[3] = dot4(*(const float4*)(Wmrg + (size_t)id * 1024 + tid * 4), m4);
    p[4] = dot4((tid < 128) ? *(const float4*)(Wrrg + (size_t)id * 512 + tid * 4) : z, o4);
#pragma unroll
    for (int d = 0; d < 5; ++d) {
      float s = p[d];
#pragma unroll
      for (int off = 32; off > 0; off >>= 1) s += __shfl_down(s, off, 64);
      if (lane == 0) red[d][wave] = s;
    }
    __syncthreads();
    if (tid == 0) {
      float D[5];
#pragma unroll
      for (int d = 0; d < 5; ++d) D[d] = red[d][0] + red[d][1] + red[d][2] + red[d][3];
      ccat[id] = b_inp[id] + b_rinp[id] + D[0];
      ccat[1024 + id] = b_ig[id] + b_mig[id] + b_rig[id] + D[1] + D[2];
      ccat[2048 + id] = b_rg[id] + b_mrg[id] + b_rrg[id] + D[3] + D[4];
    }
  } else if (id < 1536) {
    const int o = id - 1024;
    const float4 a = *(const float4*)(Who + (size_t)o * 1024 + tid * 4);
    const float4 b = *(const float4*)(b_dec + tid * 4);
    float s = dot4(a, b);
#pragma unroll
    for (int off = 32; off > 0; off >>= 1) s += __shfl_down(s, off, 64);
    if (lane == 0) red[0][wave] = s;
    __syncthreads();
    if (tid == 0) vout[o] = red[0][0] + red[0][1] + red[0][2] + red[0][3];
  } else {
    const int idx = (id - 1536) * 256 + tid;  // < 524288
    const int q = idx >> 10, k = idx & 1023;
    Wcat2[(size_t)q * 2048 + 1024 + k] = __float2bfloat16(P[idx] * mem_s[k]);
  }
}

// ================= combine: Hcat[:,0:1024] = bf16(Gbi * Gig) =================
__global__ void combine(const bf16* __restrict__ Gbi, const bf16* __restrict__ Gig,
                        bf16* __restrict__ Hcat) {
  const int i = blockIdx.x * 256 + threadIdx.x;  // < 524288 (8 elems each)
  const size_t idx8 = (size_t)i * 8;
  const int b = i >> 7;
  const int j = (int)(idx8 & 1023);
  const s16x8 x = *(const s16x8*)(Gbi + idx8);
  const s16x8 y = *(const s16x8*)(Gig + idx8);
  s16x8 o;
#pragma unroll
  for (int t = 0; t < 8; ++t) {
    const float fx = __bfloat162float(((const bf16*)&x)[t]);
    const float fy = __bfloat162float(((const bf16*)&y)[t]);
    ((bf16*)&o)[t] = __float2bfloat16(fx * fy);
  }
  *(s16x8*)(Hcat + (size_t)b * 2048 + j) = o;
}

// ================= MFMA GEMM: C[M,N] = A[M,K].B[N,K]^T, BMxBN tile, BK=64 =================
// EPI 0: raw fp32 -> pf (ld 1024).  EPI 1: gate epilogue (sigmoid, 3 destinations).
// EPI 2: fp32 out = acc + cvec[col] -> pf (ld 512).
template <int BM, int BN, int EPI>
__global__ __launch_bounds__(256, 3) void gemm_bt(const bf16* __restrict__ A,
                                                  const bf16* __restrict__ Bp, const int K,
                                                  const float* __restrict__ cvec,
                                                  bf16* __restrict__ pb0, bf16* __restrict__ pb1,
                                                  bf16* __restrict__ pb2, float* __restrict__ pf) {
  constexpr int IM = BM / 32, JN = BN / 32;
  __shared__ bf16 smem[(BM + BN) * 64];
  const int tid = threadIdx.x, wave = tid >> 6, lane = tid & 63;
  const int wm = wave >> 1, wn = wave & 1;
  const int m0 = blockIdx.y * BM, n0 = blockIdx.x * BN;
  f32x4 acc[IM][JN] = {};

  for (int kt = 0; kt < K; kt += 64) {
    __syncthreads();
#pragma unroll
    for (int i = 0; i < BM / 32; ++i) {
      const int ci = i * 256 + tid;
      const int row = ci >> 3, sck = ci & 7, ck = sck ^ (row & 7);
      const bf16* g = A + (size_t)(m0 + row) * K + kt + ck * 8;
      const unsigned lofs = (unsigned)__builtin_amdgcn_readfirstlane((i * 256 + wave * 64) * 16);
      __builtin_amdgcn_global_load_lds(
          (const __attribute__((address_space(1))) void*)g,
          (__attribute__((address_space(3))) void*)((char*)smem + lofs), 16, 0, 0);
    }
#pragma unroll
    for (int i = 0; i < BN / 32; ++i) {
      const int ci = i * 256 + tid;
      const int row = ci >> 3, sck = ci & 7, ck = sck ^ (row & 7);
      const bf16* g = Bp + (size_t)(n0 + row) * K + kt + ck * 8;
      const unsigned lofs =
          (unsigned)__builtin_amdgcn_readfirstlane(BM * 128 + (i * 256 + wave * 64) * 16);
      __builtin_amdgcn_global_load_lds(
          (const __attribute__((address_space(1))) void*)g,
          (__attribute__((address_space(3))) void*)((char*)smem + lofs), 16, 0, 0);
    }
    __syncthreads();

#pragma unroll
    for (int ks = 0; ks < 2; ++ks) {
      const int ckk = ks * 4 + (lane >> 4);
      s16x8 af[IM];
#pragma unroll
      for (int i = 0; i < IM; ++i) {
        const int R = wm * (BM / 2) + i * 16 + (lane & 15);
        af[i] = *(const s16x8*)((const char*)smem + (R * 8 + (ckk ^ (R & 7))) * 16);
      }
#pragma unroll
      for (int j = 0; j < JN; ++j) {
        const int R = wn * (BN / 2) + j * 16 + (lane & 15);
        const s16x8 bfr =
            *(const s16x8*)((const char*)smem + BM * 128 + (R * 8 + (ckk ^ (R & 7))) * 16);
#pragma unroll
        for (int i = 0; i < IM; ++i)
          acc[i][j] = __builtin_amdgcn_mfma_f32_16x16x32_bf16(af[i], bfr, acc[i][j], 0, 0, 0);
      }
    }
  }

  const int mb = (lane >> 4) * 4, nb = lane & 15;
#pragma unroll
  for (int i = 0; i < IM; ++i) {
#pragma unroll
    for (int j = 0; j < JN; ++j) {
      const int col = n0 + wn * (BN / 2) + j * 16 + nb;
#pragma unroll
      for (int r = 0; r < 4; ++r) {
        const int rowg = m0 + wm * (BM / 2) + i * 16 + mb + r;
        const float v = acc[i][j][r];
        if (EPI == 0) {
          pf[(size_t)rowg * 1024 + col] = v;
        } else if (EPI == 1) {
          const float s = sigf(v + cvec[col]);
          const int g = col >> 10, jj = col & 1023;
          if (g == 0) pb0[(size_t)rowg * 1024 + jj] = __float2bfloat16(s);
          else if (g == 1) pb1[(size_t)rowg * 1024 + jj] = __float2bfloat16(s);
          else pb2[(size_t)rowg * 2048 + 1024 + jj] = __float2bfloat16(s);
        } else {
          pf[(size_t)rowg * 512 + col] = v + cvec[col];
        }
      }
    }
  }
}

extern "C" void kernel_launch(void* const* d_in, const int* in_sizes, int n_in, void* d_out,
                              int out_size, void* d_ws, size_t ws_size, hipStream_t stream) {
  const float* input  = (const float*)d_in[0];
  const float* W_ig   = (const float*)d_in[1];  const float* b_ig   = (const float*)d_in[2];
  const float* W_rig  = (const float*)d_in[3];  const float* b_rig  = (const float*)d_in[4];
  const float* W_mig  = (const float*)d_in[5];  const float* b_mig  = (const float*)d_in[6];
  const float* W_inp  = (const float*)d_in[7];  const float* b_inp  = (const float*)d_in[8];
  const float* W_rinp = (const float*)d_in[9];  const float* b_rinp = (const float*)d_in[10];
  const float* W_rg   = (const float*)d_in[11]; const float* b_rg   = (const float*)d_in[12];
  const float* W_rrg  = (const float*)d_in[13]; const float* b_rrg  = (const float*)d_in[14];
  const float* W_mrg  = (const float*)d_in[15]; const float* b_mrg  = (const float*)d_in[16];
  const float* W_dec  = (const float*)d_in[17]; const float* b_dec  = (const float*)d_in[18];
  const float* W_wg   = (const float*)d_in[19]; const float* b_wg   = (const float*)d_in[20];
  const float* W_rwg  = (const float*)d_in[21]; const float* b_rwg  = (const float*)d_in[22];
  const float* W_mwg  = (const float*)d_in[23]; const float* b_mwg  = (const float*)d_in[24];
  const float* W_enc  = (const float*)d_in[25]; const float* b_enc  = (const float*)d_in[26];
  const float* W_ho   = (const float*)d_in[27];
  (void)W_wg; (void)W_rwg; (void)W_mwg;  // write-gate of step 4 is dead code

  char* ws = (char*)d_ws;
  float* out_s = (float*)(ws + 0);
  float* mem_s = (float*)(ws + 4096);
  float* rgm   = (float*)(ws + 8192);
  float* h0v   = (float*)(ws + 12288);
  float* wgv   = (float*)(ws + 16384);
  float* hidv  = (float*)(ws + 20480);
  float* ccat  = (float*)(ws + 24576);   // 3072 f32
  float* vout  = (float*)(ws + 36864);   // 512 f32
  float* P     = (float*)(ws + 65536);                 // [512][1024] f32 (2MB)
  bf16* Xb     = (bf16*)(ws + 2162688);                // [4096][512] (4MB)
  bf16* Wcat   = (bf16*)(ws + 6356992);                // [3072][512] (3MB)
  bf16* WhoB   = (bf16*)(ws + 9502720);                // [512][1024] (1MB)
  bf16* Wcat2  = (bf16*)(ws + 10551296);               // [512][2048] (2MB)
  bf16* Wdt    = (bf16*)(ws + 12648448);               // [1024][1024] (2MB)
  bf16* Gbi    = (bf16*)(ws + 14745600);               // [4096][1024] (8MB)
  bf16* Gig    = (bf16*)(ws + 23134208);               // [4096][1024] (8MB)
  bf16* Hcat   = (bf16*)(ws + 31522816);               // [4096][2048] (16MB)

  setup<<<11274, 256, 0, stream>>>(W_inp, W_ig, W_rg, W_ho, W_dec, input, b_inp, b_rinp, b_ig,
                                   b_mig, b_rig, b_wg, b_mwg, b_rwg, b_dec, Wcat, WhoB, Wcat2,
                                   Wdt, Xb, out_s, mem_s, hidv, wgv);

  // P = Who . W_dec  (recurrence-independent)
  gemm_bt<64, 64, 0><<<dim3(16, 8), 256, 0, stream>>>(WhoB, Wdt, 1024, nullptr, nullptr, nullptr,
                                                      nullptr, P);

  // step 0 (closed-form gates in setup) -> mem1, out1
  step_update<<<1536, 256, 0, stream>>>(W_enc, b_enc, W_ho, hidv, wgv, mem_s, out_s);

  // steps 1..3 at batch-size 1
  for (int s = 0; s < 3; ++s) {
    step_gates<<<1024, 256, 0, stream>>>(W_rinp, W_mig, W_rig, W_mrg, W_rrg, W_mwg, W_rwg, b_inp,
                                         b_rinp, b_ig, b_mig, b_rig, b_rg, b_mrg, b_rrg, b_wg,
                                         b_mwg, b_rwg, out_s, mem_s, rgm, h0v, wgv);
    step_decode<<<1024, 256, 0, stream>>>(W_dec, b_dec, rgm, h0v, hidv);
    step_update<<<1536, 256, 0, stream>>>(W_enc, b_enc, W_ho, hidv, wgv, mem_s, out_s);
  }

  // step-4 constants (ccat, vout) + Wcat2 right half = bf16(P * mem3)
  final_consts<<<3584, 256, 0, stream>>>(W_rinp, W_mig, W_rig, W_mrg, W_rrg, b_inp, b_rinp, b_ig,
                                         b_mig, b_rig, b_rg, b_mrg, b_rrg, b_dec, W_ho, out_s,
                                         mem_s, P, ccat, vout, Wcat2);

  // gates: [4096][3072] = Xb . Wcat^T, fused sigmoid epilogue
  gemm_bt<128, 128, 1><<<dim3(24, 32), 256, 0, stream>>>(Xb, Wcat, 512, ccat, Gbi, Gig, Hcat,
                                                         nullptr);
  combine<<<2048, 256, 0, stream>>>(Gbi, Gig, Hcat);

  // out = [H0|rg] . [Who|M1]^T + vout
  gemm_bt<64, 64, 2><<<dim3(8, 64), 256, 0, stream>>>(Hcat, Wcat2, 2048, vout, nullptr, nullptr,
                                                      nullptr, (float*)d_out);
}